// Round 1
// baseline (220.319 us; speedup 1.0000x reference)
//
#include <hip/hip_runtime.h>
#include <hip/hip_bf16.h>

// Problem constants
#define NN 50000
#define KK 32
#define DD 128
#define LL 64
#define NEG 0.2f

typedef __bf16 bf16x8 __attribute__((ext_vector_type(8)));
typedef unsigned short u16x8 __attribute__((ext_vector_type(8)));
typedef float f32x4 __attribute__((ext_vector_type(4)));

// RNE float -> bf16 (finite inputs only)
__device__ __forceinline__ unsigned short f2bf(float f) {
    unsigned u = __builtin_bit_cast(unsigned, f);
    unsigned r = (u + 0x7fffu + ((u >> 16) & 1u)) >> 16;
    return (unsigned short)r;
}

__device__ __forceinline__ bf16x8 pack_bf16x8(float4 a, float4 b) {
    u16x8 t;
    t[0] = f2bf(a.x); t[1] = f2bf(a.y); t[2] = f2bf(a.z); t[3] = f2bf(a.w);
    t[4] = f2bf(b.x); t[5] = f2bf(b.y); t[6] = f2bf(b.z); t[7] = f2bf(b.w);
    return __builtin_bit_cast(bf16x8, t);
}

// Prep: build swizzled bf16 LDS image of W^T in workspace.
// Wt[e][d] = linear[d][e]; byte offset b = e*256 + d*2, swizzled b ^= (e&7)<<4.
__global__ void prep_w_kernel(const float* __restrict__ lin,
                              unsigned short* __restrict__ wimg) {
    int idx = blockIdx.x * blockDim.x + threadIdx.x;   // over D*D = 16384
    if (idx >= DD * DD) return;
    int d = idx >> 7;        // row of linear (input dim)
    int e = idx & 127;       // col of linear (output dim)
    unsigned b = (unsigned)e * 256u + (unsigned)d * 2u;
    b ^= ((unsigned)(e & 7)) << 4;
    wimg[b >> 1] = f2bf(lin[idx]);
}

__global__ __launch_bounds__(256)
void attn_fused_kernel(const float* __restrict__ X,            // [N,K,D]
                       const float* __restrict__ LAB,          // [N,K,L]
                       const unsigned short* __restrict__ WIMG,// swizzled bf16 W^T (32KB)
                       const float* __restrict__ EV,           // [128]
                       const float* __restrict__ BIAS,         // [32]
                       float* __restrict__ OUT)                // [N,L]
{
    __shared__ __align__(16) unsigned short w_lds[DD * DD];    // 32 KB
    __shared__ float alpha_lds[4 * 64];                        // per-wave 2 n x 32 k

    const int tid  = threadIdx.x;
    const int wave = tid >> 6;
    const int lane = tid & 63;
    const int lo16 = lane & 15;
    const int g    = lane >> 4;        // 0..3

    // ---- stage W image into LDS (linear copy; swizzle pre-applied) ----
    {
        const float4* wsrc = reinterpret_cast<const float4*>(WIMG);
        float4* wdst = reinterpret_cast<float4*>(w_lds);
        #pragma unroll
        for (int i = 0; i < 8; ++i)
            wdst[i * 256 + tid] = wsrc[i * 256 + tid];
    }

    // ---- per-lane constants ----
    float evr[8];
    #pragma unroll
    for (int ct = 0; ct < 8; ++ct) evr[ct] = EV[ct * 16 + lo16];

    float biasr[2][4];
    #pragma unroll
    for (int h = 0; h < 2; ++h)
        #pragma unroll
        for (int r = 0; r < 4; ++r)
            biasr[h][r] = BIAS[h * 16 + g * 4 + r];

    // ---- A fragments: global -> reg, fp32 -> bf16 ----
    // wave handles 64 rows (= 2 n's); block handles 256 rows (= 8 n's)
    const long rowbase = (long)blockIdx.x * 256 + wave * 64;
    bf16x8 a[4][4];
    #pragma unroll
    for (int mt = 0; mt < 4; ++mt) {
        const float* xr = X + (rowbase + mt * 16 + lo16) * (long)DD;
        #pragma unroll
        for (int kt = 0; kt < 4; ++kt) {
            const float4* p = reinterpret_cast<const float4*>(xr + kt * 32 + g * 8);
            float4 u0 = p[0];
            float4 u1 = p[1];
            a[mt][kt] = pack_bf16x8(u0, u1);
        }
    }

    __syncthreads();   // W staged

    // ---- MFMA main: 8 col-tiles x 4 m-tiles x 4 k-tiles ----
    float pe[4][4];
    #pragma unroll
    for (int mt = 0; mt < 4; ++mt)
        #pragma unroll
        for (int r = 0; r < 4; ++r) pe[mt][r] = 0.f;

    const char* wl = reinterpret_cast<const char*>(w_lds);
    #pragma unroll
    for (int ct = 0; ct < 8; ++ct) {
        bf16x8 b[4];
        const int n = ct * 16 + lo16;          // B col (output dim e)
        #pragma unroll
        for (int kt = 0; kt < 4; ++kt) {
            unsigned off = (unsigned)(n * 256 + kt * 64 + g * 16);
            off ^= ((unsigned)(n & 7)) << 4;
            b[kt] = *reinterpret_cast<const bf16x8*>(wl + off);
        }
        f32x4 acc[4];
        #pragma unroll
        for (int mt = 0; mt < 4; ++mt) { acc[mt][0]=0.f; acc[mt][1]=0.f; acc[mt][2]=0.f; acc[mt][3]=0.f; }
        #pragma unroll
        for (int kt = 0; kt < 4; ++kt)
            #pragma unroll
            for (int mt = 0; mt < 4; ++mt)
                acc[mt] = __builtin_amdgcn_mfma_f32_16x16x32_bf16(a[mt][kt], b[kt], acc[mt], 0, 0, 0);
        // epilogue: LeakyReLU(h) * ev[col], accumulate per-row partials
        #pragma unroll
        for (int mt = 0; mt < 4; ++mt)
            #pragma unroll
            for (int r = 0; r < 4; ++r) {
                float h = acc[mt][r];
                h = (h > 0.f) ? h : NEG * h;
                pe[mt][r] += h * evr[ct];
            }
    }

    // ---- reduce over the 16 col-lanes; bias + LeakyReLU ----
    // lane holds rows mt*16 + g*4 + r (C/D layout), replicated over lo16 after reduce
    #pragma unroll
    for (int mt = 0; mt < 4; ++mt)
        #pragma unroll
        for (int r = 0; r < 4; ++r) {
            float v = pe[mt][r];
            v += __shfl_xor(v, 1);
            v += __shfl_xor(v, 2);
            v += __shfl_xor(v, 4);
            v += __shfl_xor(v, 8);
            v += biasr[mt & 1][r];
            pe[mt][r] = (v > 0.f) ? v : NEG * v;
        }

    // ---- softmax over K=32 per n (2 n's per wave) ----
    #pragma unroll
    for (int h = 0; h < 2; ++h) {
        float m = -3.4e38f;
        #pragma unroll
        for (int t = 0; t < 2; ++t)
            #pragma unroll
            for (int r = 0; r < 4; ++r) m = fmaxf(m, pe[2 * h + t][r]);
        m = fmaxf(m, __shfl_xor(m, 16));
        m = fmaxf(m, __shfl_xor(m, 32));
        float p[2][4];
        float s = 0.f;
        #pragma unroll
        for (int t = 0; t < 2; ++t)
            #pragma unroll
            for (int r = 0; r < 4; ++r) {
                p[t][r] = __expf(pe[2 * h + t][r] - m);
                s += p[t][r];
            }
        s += __shfl_xor(s, 16);
        s += __shfl_xor(s, 32);
        float inv = 1.f / s;
        if (lo16 == 0) {
            #pragma unroll
            for (int t = 0; t < 2; ++t)
                #pragma unroll
                for (int r = 0; r < 4; ++r)
                    alpha_lds[wave * 64 + h * 32 + t * 16 + g * 4 + r] = p[t][r] * inv;
        }
    }

    __syncthreads();

    // ---- label aggregation: out[n][l] = sum_k alpha[k] * labels[n][k][l] ----
    const int c2 = (lane & 31) * 2;     // column pair
    const int kh = lane >> 5;           // k half (0: k<16, 1: k>=16)
    #pragma unroll
    for (int h = 0; h < 2; ++h) {
        const long n = (long)blockIdx.x * 8 + wave * 2 + h;
        const float* lab = LAB + n * (long)(KK * LL) + kh * 16 * LL + c2;
        float ax = 0.f, ay = 0.f;
        #pragma unroll
        for (int k = 0; k < 16; ++k) {
            float al = alpha_lds[wave * 64 + h * 32 + kh * 16 + k];
            float2 lv = *reinterpret_cast<const float2*>(lab + k * LL);
            ax += al * lv.x;
            ay += al * lv.y;
        }
        ax += __shfl_xor(ax, 32);
        ay += __shfl_xor(ay, 32);
        if (lane < 32) {
            float2 o;
            o.x = ax; o.y = ay;
            *reinterpret_cast<float2*>(OUT + n * LL + c2) = o;
        }
    }
}

extern "C" void kernel_launch(void* const* d_in, const int* in_sizes, int n_in,
                              void* d_out, int out_size, void* d_ws, size_t ws_size,
                              hipStream_t stream) {
    const float* X    = (const float*)d_in[0];   // [50000,32,128]
    const float* LAB  = (const float*)d_in[1];   // [50000,32,64]
    const float* LIN  = (const float*)d_in[2];   // [128,128]
    const float* EV   = (const float*)d_in[3];   // [128]
    const float* BIAS = (const float*)d_in[4];   // [32]
    float* OUT = (float*)d_out;
    unsigned short* wimg = (unsigned short*)d_ws;  // 32 KB swizzled bf16 W^T

    prep_w_kernel<<<64, 256, 0, stream>>>(LIN, wimg);
    attn_fused_kernel<<<NN / 8, 256, 0, stream>>>(X, LAB, wimg, EV, BIAS, OUT);
}